// Round 8
// baseline (518.097 us; speedup 1.0000x reference)
//
#include <hip/hip_runtime.h>
#include <math.h>

#define BATCH 4
#define NPTS 8192
#define GS 32
#define NCELLS (GS*GS*GS)          // 32768 per batch
#define GMIN (-4.0f)
#define CS 0.25f
#define INVCS 4.0f
#define FINF 3.4e38f
#define LPQ 8                      // lanes per query

__device__ __forceinline__ int cellco(float v) {
    int c = (int)floorf((v - GMIN) * INVCS);
    return min(max(c, 0), GS - 1);
}

// ---------------------------------------------------------------------------
// Pass 1: histogram of warped candidates into the grid.
// ---------------------------------------------------------------------------
__global__ __launch_bounds__(256) void bin_count_kernel(
    const float* __restrict__ xyz1, const float* __restrict__ flow1,
    int* __restrict__ counts)
{
    int t = blockIdx.x * 256 + threadIdx.x;       // BATCH*NPTS threads
    int b = t >> 13, n = t & (NPTS - 1);
    const float* x = xyz1 + b * 3 * NPTS + n;
    const float* f = flow1 + b * 3 * NPTS + n;
    float wx = x[0] + f[0], wy = x[NPTS] + f[NPTS], wz = x[2*NPTS] + f[2*NPTS];
    int gc = ((b * GS + cellco(wz)) * GS + cellco(wy)) * GS + cellco(wx);
    atomicAdd(&counts[gc], 1);
}

// ---------------------------------------------------------------------------
// Pass 2: exclusive prefix scan per batch (4 blocks x 1024 threads, 32
// cells/thread serial + Hillis-Steele over 1024 partials in LDS).
// Writes cellStart and a working copy (cursor) for the scatter pass.
// ---------------------------------------------------------------------------
__global__ __launch_bounds__(1024) void scan_cells_kernel(
    const int* __restrict__ counts, int* __restrict__ cellStart,
    int* __restrict__ cursor)
{
    __shared__ int part[1024];
    int b = blockIdx.x;
    int t = (int)threadIdx.x;
    const int CPB = NCELLS / 1024;                // 32
    int base = b * NCELLS + t * CPB;

    int local[CPB];
    int s = 0;
    #pragma unroll
    for (int i = 0; i < CPB; ++i) { local[i] = s; s += counts[base + i]; }
    part[t] = s;
    __syncthreads();
    for (int off = 1; off < 1024; off <<= 1) {
        int v = (t >= off) ? part[t - off] : 0;
        __syncthreads();
        part[t] += v;
        __syncthreads();
    }
    int tbase = b * NPTS + (t ? part[t - 1] : 0);
    #pragma unroll
    for (int i = 0; i < CPB; ++i) {
        int v = tbase + local[i];
        cellStart[base + i] = v;
        cursor[base + i]    = v;
    }
    if (b == 0 && t == 0) cellStart[BATCH * NCELLS] = BATCH * NPTS;
}

// ---------------------------------------------------------------------------
// Pass 3: scatter candidates into cell-sorted order. ckey holds the scan key
// (-2x,-2y,-2z,|c|^2) (same expansion form as the reference's selection);
// cflow holds the candidate's flow so downstream never needs original indices.
// Intra-cell order is atomic-nondeterministic; with continuous random data
// exact key ties are measure-zero, so the selected 3-NN set is deterministic.
// ---------------------------------------------------------------------------
__global__ __launch_bounds__(256) void scatter_kernel(
    const float* __restrict__ xyz1, const float* __restrict__ flow1,
    int* __restrict__ cursor, float4* __restrict__ ckey,
    float4* __restrict__ cflow)
{
    int t = blockIdx.x * 256 + threadIdx.x;
    int b = t >> 13, n = t & (NPTS - 1);
    const float* x = xyz1 + b * 3 * NPTS + n;
    const float* f = flow1 + b * 3 * NPTS + n;
    float fx = f[0], fy = f[NPTS], fz = f[2*NPTS];
    float wx = x[0] + fx, wy = x[NPTS] + fy, wz = x[2*NPTS] + fz;
    float nrm = fmaf(wx, wx, fmaf(wy, wy, wz * wz));
    int gc = ((b * GS + cellco(wz)) * GS + cellco(wy)) * GS + cellco(wx);
    int pos = atomicAdd(&cursor[gc], 1);
    ckey[pos]  = make_float4(-2.0f * wx, -2.0f * wy, -2.0f * wz, nrm);
    cflow[pos] = make_float4(fx, fy, fz, 0.0f);
}

// ---------------------------------------------------------------------------
// Pass 4: exact 3-NN by expanding Chebyshev shells + fused IDW epilogue.
// 8 lanes per query; shell cells round-robined by (cnt & 7) == sub; partial
// top-3s merged with shfl_xor(1,2,4). Validity: e2_true <= margin^2 with
// margin = distance from q to the visited-box boundary, ignoring faces at
// the grid edge (no unscanned candidates beyond them; clamped points lie at
// least as far as their cell). s=31 always covers the grid => terminates.
// ---------------------------------------------------------------------------
__device__ __forceinline__ void insert3(float d, int idx,
    float& e0, float& e1, float& e2, int& i0, int& i1, int& i2)
{
    if (d < e2) {
        bool c1 = d < e1, c0 = d < e0;
        float t1 = __builtin_amdgcn_fmed3f(e0, e1, d);
        float t2 = __builtin_amdgcn_fmed3f(e1, e2, d);
        i2 = c1 ? i1 : idx;
        i1 = c0 ? i0 : (c1 ? idx : i1);
        i0 = c0 ? idx : i0;
        e0 = fminf(e0, d); e1 = t1; e2 = t2;
    }
}

__global__ __launch_bounds__(256) void knn_kernel(
    const float* __restrict__ xyz2,
    const float4* __restrict__ ckey, const float4* __restrict__ cflow,
    const int* __restrict__ cellStart, float* __restrict__ out)
{
    int g   = blockIdx.x * 256 + (int)threadIdx.x;   // BATCH*NPTS*LPQ threads
    int sub = g & (LPQ - 1);
    int qid = g >> 3;
    int b   = qid >> 13, j = qid & (NPTS - 1);

    const float* qp = xyz2 + b * 3 * NPTS + j;
    float qx = qp[0], qy = qp[NPTS], qz = qp[2 * NPTS];
    float qn = fmaf(qx, qx, fmaf(qy, qy, qz * qz));

    int hx = cellco(qx), hy = cellco(qy), hz = cellco(qz);

    float e0 = FINF, e1 = FINF, e2 = FINF;
    int   i0 = 0, i1 = 0, i2 = 0;
    float m0, m1, m2; int n0, n1, n2;
    int cnt = 0;

    for (int s = 0; s < GS; ++s) {
        for (int dz = -s; dz <= s; ++dz) {
            int z = hz + dz; if (z < 0 || z >= GS) continue;
            for (int dy = -s; dy <= s; ++dy) {
                int y = hy + dy; if (y < 0 || y >= GS) continue;
                bool face = (dz == -s || dz == s || dy == -s || dy == s);
                int step = face ? 1 : (2 * s);       // interior rows: dx=+-s only
                for (int dx = -s; dx <= s; dx += step) {
                    int x = hx + dx; if (x < 0 || x >= GS) continue;
                    if ((cnt++ & (LPQ - 1)) != sub) continue;
                    int gc = ((b * GS + z) * GS + y) * GS + x;
                    int st = cellStart[gc], en = cellStart[gc + 1];
                    for (int k = st; k < en; ++k) {
                        float4 c = ckey[k];
                        float d = fmaf(c.x, qx, fmaf(c.y, qy, fmaf(c.z, qz, c.w)));
                        if (d < e2) {
                            bool c0 = d < e0, c1 = d < e1;
                            float t1 = __builtin_amdgcn_fmed3f(e0, e1, d);
                            float t2 = __builtin_amdgcn_fmed3f(e1, e2, d);
                            i2 = c1 ? i1 : k;
                            i1 = c0 ? i0 : (c1 ? k : i1);
                            i0 = c0 ? k : i0;
                            e0 = fminf(e0, d); e1 = t1; e2 = t2;
                        }
                    }
                }
            }
        }
        // merge the 8 partial top-3s (symmetric butterfly; all lanes converge)
        m0 = e0; m1 = e1; m2 = e2; n0 = i0; n1 = i1; n2 = i2;
        #pragma unroll
        for (int w = 1; w <= 4; w <<= 1) {
            float r0 = __shfl_xor(m0, w), r1 = __shfl_xor(m1, w), r2 = __shfl_xor(m2, w);
            int   s0 = __shfl_xor(n0, w), s1 = __shfl_xor(n1, w), s2 = __shfl_xor(n2, w);
            insert3(r0, s0, m0, m1, m2, n0, n1, n2);
            insert3(r1, s1, m0, m1, m2, n0, n1, n2);
            insert3(r2, s2, m0, m1, m2, n0, n1, n2);
        }
        bool full = (hx - s <= 0) && (hx + s >= GS - 1) &&
                    (hy - s <= 0) && (hy + s >= GS - 1) &&
                    (hz - s <= 0) && (hz + s >= GS - 1);
        if (full) break;
        float mg = FINF;
        if (hx - s > 0)      mg = fminf(mg, qx - (GMIN + (hx - s) * CS));
        if (hx + s < GS - 1) mg = fminf(mg, (GMIN + (hx + s + 1) * CS) - qx);
        if (hy - s > 0)      mg = fminf(mg, qy - (GMIN + (hy - s) * CS));
        if (hy + s < GS - 1) mg = fminf(mg, (GMIN + (hy + s + 1) * CS) - qy);
        if (hz - s > 0)      mg = fminf(mg, qz - (GMIN + (hz - s) * CS));
        if (hz + s < GS - 1) mg = fminf(mg, (GMIN + (hz + s + 1) * CS) - qz);
        if (m2 + qn <= mg * mg) break;   // true 3rd-NN dist^2 <= unvisited bound
    }

    if (sub == 0) {
        float wsum = 0.f, f2x = 0.f, f2y = 0.f, f2z = 0.f;
        int idxs[3] = { n0, n1, n2 };
        #pragma unroll
        for (int k = 0; k < 3; ++k) {
            int id = idxs[k];
            float4 c = ckey[id];
            float cx = -0.5f * c.x, cy = -0.5f * c.y, cz = -0.5f * c.z;  // exact
            float dx = cx - qx, dy = cy - qy, dz = cz - qz;
            float dist = sqrtf(fmaf(dx, dx, fmaf(dy, dy, dz * dz)));
            dist = fmaxf(dist, 1e-10f);
            float w = 1.0f / dist;
            wsum += w;
            float4 fl = cflow[id];
            f2x = fmaf(w, fl.x, f2x);
            f2y = fmaf(w, fl.y, f2y);
            f2z = fmaf(w, fl.z, f2z);
        }
        float r = 1.0f / wsum;
        float* ob = out + b * 3 * NPTS;
        ob[j]            = qx - f2x * r;
        ob[NPTS + j]     = qy - f2y * r;
        ob[2 * NPTS + j] = qz - f2z * r;
    }
}

// ---------------------------------------------------------------------------
// Launcher. Workspace (~2.6 MB, well under available):
//   ckey 512K | cflow 512K | counts 512K | cellStart 512K+64 | cursor 512K
// ---------------------------------------------------------------------------
extern "C" void kernel_launch(void* const* d_in, const int* in_sizes, int n_in,
                              void* d_out, int out_size, void* d_ws, size_t ws_size,
                              hipStream_t stream)
{
    const float* xyz1  = (const float*)d_in[0];
    const float* xyz2  = (const float*)d_in[1];
    const float* flow1 = (const float*)d_in[2];
    float* out = (float*)d_out;

    char* p = (char*)d_ws;
    float4* ckey      = (float4*)p;                      p += (size_t)BATCH * NPTS * 16;
    float4* cflow     = (float4*)p;                      p += (size_t)BATCH * NPTS * 16;
    int*    counts    = (int*)p;                         p += (size_t)BATCH * NCELLS * 4;
    int*    cellStart = (int*)p;                         p += ((size_t)BATCH * NCELLS + 16) * 4;
    int*    cursor    = (int*)p;

    hipMemsetAsync(counts, 0, (size_t)BATCH * NCELLS * 4, stream);
    bin_count_kernel <<<BATCH * NPTS / 256, 256, 0, stream>>>(xyz1, flow1, counts);
    scan_cells_kernel<<<BATCH, 1024, 0, stream>>>(counts, cellStart, cursor);
    scatter_kernel   <<<BATCH * NPTS / 256, 256, 0, stream>>>(xyz1, flow1, cursor, ckey, cflow);
    knn_kernel       <<<BATCH * NPTS * LPQ / 256, 256, 0, stream>>>(xyz2, ckey, cflow, cellStart, out);
}